// Round 1
// baseline (15422.112 us; speedup 1.0000x reference)
//
#include <hip/hip_runtime.h>
#include <math.h>

#define NPB 32  // nodes per block in GRU step kernel

struct GruParams {
  const float* x;      // [N, T, 64]
  const float* wt4ih;  // [16][768][4]  (k-blocked transpose of W_ih [768,64])
  const float* wt4hh;  // [64][768][4]  (k-blocked transpose of W_hh [768,256])
  const float* bih;    // [768]
  const float* bhh;    // [768]
  int T;
  int off;             // column offset in comb (0/256/512)
};
struct GruAll { GruParams g[3]; };

// dst[((k>>2)*768 + j)*4 + (k&3)] = src[j*K + k]
__global__ void prep_wt4(const float* __restrict__ src, float* __restrict__ dst, int K) {
  int idx = blockIdx.x * blockDim.x + threadIdx.x;
  int total = 768 * K;
  if (idx >= total) return;
  int j = idx / K, k = idx - j * K;
  dst[((size_t)(k >> 2) * 768 + j) * 4 + (k & 3)] = src[idx];
}

__launch_bounds__(256, 2)
__global__ void gru_step(GruAll ga, float* __restrict__ comb, int t, int N) {
  const GruParams gp = ga.g[blockIdx.y];
  if (t >= gp.T) return;
  __shared__ float h_tile[NPB][256];
  __shared__ float x_tile[NPB][64];
  const int tid = threadIdx.x;
  const int nb = blockIdx.x * NPB;
  const int nvalid = (N - nb < NPB) ? (N - nb) : NPB;

  // stage x_t for 32 nodes
  #pragma unroll
  for (int i = 0; i < (NPB * 64) / 256; ++i) {
    int l = i * 256 + tid;
    int n = l >> 6, f = l & 63;
    float v = 0.f;
    if (n < nvalid) v = gp.x[((size_t)(nb + n) * gp.T + t) * 64 + f];
    x_tile[n][f] = v;
  }
  // stage h for 32 nodes
  if (t == 0) {
    #pragma unroll
    for (int i = 0; i < NPB; ++i) h_tile[i][tid] = 0.f;
  } else {
    #pragma unroll
    for (int i = 0; i < NPB; ++i) {
      float v = 0.f;
      if (i < nvalid) v = comb[(size_t)(nb + i) * 768 + gp.off + tid];
      h_tile[i][tid] = v;
    }
  }
  __syncthreads();

  const int j = tid;
  float accr[NPB], accz[NPB], accni[NPB], accnh[NPB];
  #pragma unroll
  for (int n = 0; n < NPB; ++n) { accr[n] = 0.f; accz[n] = 0.f; accni[n] = 0.f; accnh[n] = 0.f; }

  // input projection: K=64
  const float4* __restrict__ wih = reinterpret_cast<const float4*>(gp.wt4ih);
  #pragma unroll 2
  for (int k4 = 0; k4 < 16; ++k4) {
    float4 wr = wih[k4 * 768 + j];
    float4 wz = wih[k4 * 768 + 256 + j];
    float4 wn = wih[k4 * 768 + 512 + j];
    #pragma unroll
    for (int n = 0; n < NPB; ++n) {
      float4 xv = *reinterpret_cast<const float4*>(&x_tile[n][k4 * 4]);
      accr[n]  += wr.x * xv.x + wr.y * xv.y + wr.z * xv.z + wr.w * xv.w;
      accz[n]  += wz.x * xv.x + wz.y * xv.y + wz.z * xv.z + wz.w * xv.w;
      accni[n] += wn.x * xv.x + wn.y * xv.y + wn.z * xv.z + wn.w * xv.w;
    }
  }
  // hidden projection: K=256
  const float4* __restrict__ whh = reinterpret_cast<const float4*>(gp.wt4hh);
  #pragma unroll 1
  for (int k4 = 0; k4 < 64; ++k4) {
    float4 wr = whh[k4 * 768 + j];
    float4 wz = whh[k4 * 768 + 256 + j];
    float4 wn = whh[k4 * 768 + 512 + j];
    #pragma unroll
    for (int n = 0; n < NPB; ++n) {
      float4 hv = *reinterpret_cast<const float4*>(&h_tile[n][k4 * 4]);
      accr[n]  += wr.x * hv.x + wr.y * hv.y + wr.z * hv.z + wr.w * hv.w;
      accz[n]  += wz.x * hv.x + wz.y * hv.y + wz.z * hv.z + wz.w * hv.w;
      accnh[n] += wn.x * hv.x + wn.y * hv.y + wn.z * hv.z + wn.w * hv.w;
    }
  }

  const float bir = gp.bih[j], biz = gp.bih[256 + j], bin_ = gp.bih[512 + j];
  const float bhr = gp.bhh[j], bhz = gp.bhh[256 + j], bhn = gp.bhh[512 + j];
  #pragma unroll
  for (int n = 0; n < NPB; ++n) {
    if (n < nvalid) {
      float r = 1.f / (1.f + expf(-(accr[n] + bir + bhr)));
      float z = 1.f / (1.f + expf(-(accz[n] + biz + bhz)));
      float nn = tanhf(accni[n] + bin_ + r * (accnh[n] + bhn));
      float hold = h_tile[n][j];
      comb[(size_t)(nb + n) * 768 + gp.off + j] = (1.f - z) * nn + z * hold;
    }
  }
}

// C[m,n] = act( sum_k A[m,k]*B[n,k] + bias[n] ), A:[M,K] rm, B:[N,K] rm. N multiple of 64, K mult of 16.
__launch_bounds__(256, 2)
__global__ void gemm_nt(const float* __restrict__ A, const float* __restrict__ B,
                        const float* __restrict__ bias, float* __restrict__ C,
                        int M, int N, int K, int do_relu) {
  __shared__ float As[16][68];
  __shared__ float Bs[16][68];
  const int tid = threadIdx.x;
  const int m0 = blockIdx.x * 64, n0 = blockIdx.y * 64;
  const int lrow = tid >> 2;          // 0..63
  const int lk = (tid & 3) * 4;       // 0,4,8,12
  const int tx = tid & 15, ty = tid >> 4;
  float acc[4][4] = {};
  for (int k0 = 0; k0 < K; k0 += 16) {
    float4 a4 = {0.f, 0.f, 0.f, 0.f};
    int gm = m0 + lrow;
    if (gm < M) a4 = *reinterpret_cast<const float4*>(&A[(size_t)gm * K + k0 + lk]);
    float4 b4 = *reinterpret_cast<const float4*>(&B[(size_t)(n0 + lrow) * K + k0 + lk]);
    __syncthreads();
    As[lk + 0][lrow] = a4.x; As[lk + 1][lrow] = a4.y; As[lk + 2][lrow] = a4.z; As[lk + 3][lrow] = a4.w;
    Bs[lk + 0][lrow] = b4.x; Bs[lk + 1][lrow] = b4.y; Bs[lk + 2][lrow] = b4.z; Bs[lk + 3][lrow] = b4.w;
    __syncthreads();
    #pragma unroll
    for (int kk = 0; kk < 16; ++kk) {
      float4 av = *reinterpret_cast<const float4*>(&As[kk][ty * 4]);
      float4 bv = *reinterpret_cast<const float4*>(&Bs[kk][tx * 4]);
      float a[4] = {av.x, av.y, av.z, av.w};
      float b[4] = {bv.x, bv.y, bv.z, bv.w};
      #pragma unroll
      for (int i = 0; i < 4; ++i)
        #pragma unroll
        for (int jj = 0; jj < 4; ++jj) acc[i][jj] += a[i] * b[jj];
    }
  }
  #pragma unroll
  for (int i = 0; i < 4; ++i) {
    int gm = m0 + ty * 4 + i;
    if (gm >= M) continue;
    #pragma unroll
    for (int jj = 0; jj < 4; ++jj) {
      int gn = n0 + tx * 4 + jj;
      float v = acc[i][jj] + (bias ? bias[gn] : 0.f);
      if (do_relu) v = fmaxf(v, 0.f);
      C[(size_t)gm * N + gn] = v;
    }
  }
}

__device__ inline unsigned enc_f32(float f) {
  unsigned b = __float_as_uint(f);
  return (b & 0x80000000u) ? ~b : (b | 0x80000000u);
}
__device__ inline float dec_f32(unsigned u) {
  return __uint_as_float((u & 0x80000000u) ? (u ^ 0x80000000u) : ~u);
}

// p1[n] = dot(aw[0:256], xl[n]); p2[n] = dot(aw[256:512], xl[n])  (one wave per node)
__global__ void p12_kernel(const float* __restrict__ xl, const float* __restrict__ aw,
                           float* __restrict__ p1, float* __restrict__ p2, int N) {
  int node = blockIdx.x * 4 + (threadIdx.x >> 6);
  int lane = threadIdx.x & 63;
  if (node >= N) return;
  float4 v  = reinterpret_cast<const float4*>(&xl[(size_t)node * 256])[lane];
  float4 a1 = reinterpret_cast<const float4*>(aw)[lane];
  float4 a2 = reinterpret_cast<const float4*>(aw + 256)[lane];
  float s1 = v.x * a1.x + v.y * a1.y + v.z * a1.z + v.w * a1.w;
  float s2 = v.x * a2.x + v.y * a2.y + v.z * a2.z + v.w * a2.w;
  #pragma unroll
  for (int o = 32; o > 0; o >>= 1) { s1 += __shfl_down(s1, o); s2 += __shfl_down(s2, o); }
  if (lane == 0) { p1[node] = s1; p2[node] = s2; }
}

__global__ void edge_scores(const int* __restrict__ ei, const float* __restrict__ ew,
                            const float* __restrict__ p1, const float* __restrict__ p2,
                            const float* __restrict__ awe, const float* __restrict__ ab,
                            float* __restrict__ scores, unsigned* __restrict__ segmax, int E) {
  int e = blockIdx.x * blockDim.x + threadIdx.x;
  if (e >= E) return;
  int r = ei[e], c = ei[E + e];
  float s = p1[r] + p2[c] + awe[0] * ew[e] + ab[0];
  scores[e] = s;
  atomicMax(&segmax[r], enc_f32(s));
}

__global__ void edge_expsum(const int* __restrict__ ei, const float* __restrict__ scores,
                            const unsigned* __restrict__ segmax, float* __restrict__ alpha,
                            float* __restrict__ segsum, int E) {
  int e = blockIdx.x * blockDim.x + threadIdx.x;
  if (e >= E) return;
  int r = ei[e];
  float a = expf(scores[e] - dec_f32(segmax[r]));
  alpha[e] = a;
  atomicAdd(&segsum[r], a);
}

// one block (256 threads) per edge; agg[col] += (alpha/segsum[row]) * xl[row]
__global__ void sage_aggregate(const float* __restrict__ xl, const int* __restrict__ ei,
                               const float* __restrict__ alpha, const float* __restrict__ segsum,
                               float* __restrict__ agg, int E) {
  int e = blockIdx.x;
  int d = threadIdx.x;
  int r = ei[e], c = ei[E + e];
  float w = alpha[e] / (segsum[r] + 1e-16f);
  atomicAdd(&agg[(size_t)c * 256 + d], w * xl[(size_t)r * 256 + d]);
}

__global__ void relu_copy(const float* __restrict__ in, float* __restrict__ out, int n) {
  int i = blockIdx.x * blockDim.x + threadIdx.x;
  if (i < n) out[i] = fmaxf(in[i], 0.f);
}

__global__ void relu_add(float* __restrict__ agg, const float* __restrict__ temb, int n) {
  int i = blockIdx.x * blockDim.x + threadIdx.x;
  if (i < n) agg[i] = fmaxf(agg[i], 0.f) + temb[i];
}

__global__ void head_kernel(const float* __restrict__ g2, const float* __restrict__ impW,
                            const float* __restrict__ impb, const float* __restrict__ uncW,
                            const float* __restrict__ uncb, float* __restrict__ out, int N) {
  int node = blockIdx.x * 4 + (threadIdx.x >> 6);
  int lane = threadIdx.x & 63;
  if (node >= N) return;
  float4 v  = reinterpret_cast<const float4*>(&g2[(size_t)node * 256])[lane];
  float4 wi = reinterpret_cast<const float4*>(impW)[lane];
  float4 wu = reinterpret_cast<const float4*>(uncW)[lane];
  float si = v.x * wi.x + v.y * wi.y + v.z * wi.z + v.w * wi.w;
  float su = v.x * wu.x + v.y * wu.y + v.z * wu.z + v.w * wu.w;
  #pragma unroll
  for (int o = 32; o > 0; o >>= 1) { si += __shfl_down(si, o); su += __shfl_down(su, o); }
  if (lane == 0) {
    out[node] = tanhf(si + impb[0]);
    out[N + node] = 1.f / (1.f + expf(-(su + uncb[0])));
  }
}

extern "C" void kernel_launch(void* const* d_in, const int* in_sizes, int n_in,
                              void* d_out, int out_size, void* d_ws, size_t ws_size,
                              hipStream_t stream) {
  const float* xs  = (const float*)d_in[0];
  const float* xm  = (const float*)d_in[1];
  const float* xlg = (const float*)d_in[2];
  const int*   ei  = (const int*)d_in[3];
  const float* ea  = (const float*)d_in[4];
  const float* W[3][4];
  for (int g = 0; g < 3; ++g)
    for (int q = 0; q < 4; ++q)
      W[g][q] = (const float*)d_in[5 + g * 4 + q];
  const float* fW   = (const float*)d_in[17];
  const float* fb   = (const float*)d_in[18];
  const float* g1W  = (const float*)d_in[19];
  const float* g1aw = (const float*)d_in[20];
  const float* g1ab = (const float*)d_in[21];
  const float* g2W  = (const float*)d_in[22];
  const float* g2aw = (const float*)d_in[23];
  const float* g2ab = (const float*)d_in[24];
  const float* impW = (const float*)d_in[25];
  const float* impb = (const float*)d_in[26];
  const float* uncW = (const float*)d_in[27];
  const float* uncb = (const float*)d_in[28];
  float* out = (float*)d_out;

  const int N = in_sizes[0] / (8 * 64);   // 10000
  const int E = in_sizes[4];              // 320000

  // workspace layout (floats)
  float* ws    = (float*)d_ws;
  float* comb  = ws;                              // N*768
  float* temb  = comb + (size_t)N * 768;          // N*256
  float* xl    = temb + (size_t)N * 256;          // N*256
  float* agg   = xl   + (size_t)N * 256;          // N*256
  float* g1    = agg  + (size_t)N * 256;          // N*256
  float* scores = g1  + (size_t)N * 256;          // E
  float* alpha  = scores + E;                     // E
  float* p1     = alpha + E;                      // N
  float* p2     = p1 + N;                         // N
  unsigned* segmax = (unsigned*)(p2 + N);         // N
  float* segsum = (float*)(segmax + N);           // N
  float* p = segsum + N;
  float* wt4ih[3]; float* wt4hh[3];
  for (int g = 0; g < 3; ++g) { wt4ih[g] = p; p += 768 * 64; }
  for (int g = 0; g < 3; ++g) { wt4hh[g] = p; p += 768 * 256; }
  size_t need_bytes = (size_t)(p - ws) * sizeof(float);
  if (ws_size < need_bytes) return;  // insufficient scratch; fail visibly

  // one-time (per call) weight transposes
  for (int g = 0; g < 3; ++g) {
    prep_wt4<<<(768 * 64 + 255) / 256, 256, 0, stream>>>(W[g][0], wt4ih[g], 64);
    prep_wt4<<<(768 * 256 + 255) / 256, 256, 0, stream>>>(W[g][1], wt4hh[g], 256);
  }

  GruAll ga;
  const float* xsrc[3] = {xs, xm, xlg};
  const int Ts[3] = {8, 30, 60};
  for (int g = 0; g < 3; ++g) {
    ga.g[g].x = xsrc[g];
    ga.g[g].wt4ih = wt4ih[g];
    ga.g[g].wt4hh = wt4hh[g];
    ga.g[g].bih = W[g][2];
    ga.g[g].bhh = W[g][3];
    ga.g[g].T = Ts[g];
    ga.g[g].off = g * 256;
  }
  dim3 ggrid((N + NPB - 1) / NPB, 3);
  for (int t = 0; t < 60; ++t)
    gru_step<<<ggrid, 256, 0, stream>>>(ga, comb, t, N);

  // temporal_emb = relu(comb @ fW^T + fb)
  gemm_nt<<<dim3((N + 63) / 64, 4), 256, 0, stream>>>(comb, fW, fb, temb, N, 256, 768, 1);

  const float* feat = temb;
  const float* gW_[2]  = {g1W, g2W};
  const float* gaw_[2] = {g1aw, g2aw};
  const float* gab_[2] = {g1ab, g2ab};
  for (int L = 0; L < 2; ++L) {
    hipMemsetAsync(agg, 0, (size_t)N * 256 * sizeof(float), stream);
    hipMemsetAsync(segmax, 0, (size_t)N * sizeof(unsigned), stream);
    hipMemsetAsync(segsum, 0, (size_t)N * sizeof(float), stream);
    gemm_nt<<<dim3((N + 63) / 64, 4), 256, 0, stream>>>(feat, gW_[L], nullptr, xl, N, 256, 256, 0);
    p12_kernel<<<(N + 3) / 4, 256, 0, stream>>>(xl, gaw_[L], p1, p2, N);
    edge_scores<<<(E + 255) / 256, 256, 0, stream>>>(ei, ea, p1, p2, gaw_[L] + 512, gab_[L], scores, segmax, E);
    edge_expsum<<<(E + 255) / 256, 256, 0, stream>>>(ei, scores, segmax, alpha, segsum, E);
    sage_aggregate<<<E, 256, 0, stream>>>(xl, ei, alpha, segsum, agg, E);
    if (L == 0) {
      relu_copy<<<((N * 256) + 255) / 256, 256, 0, stream>>>(agg, g1, N * 256);
      feat = g1;
    } else {
      relu_add<<<((N * 256) + 255) / 256, 256, 0, stream>>>(agg, temb, N * 256);
    }
  }

  head_kernel<<<(N + 3) / 4, 256, 0, stream>>>(agg, impW, impb, uncW, uncb, out, N);
}